// Round 10
// baseline (226.172 us; speedup 1.0000x reference)
//
#include <hip/hip_runtime.h>

typedef _Float16 half8 __attribute__((ext_vector_type(8)));
typedef float f32x4 __attribute__((ext_vector_type(4)));
typedef unsigned int uint;
typedef uint uint2v __attribute__((ext_vector_type(2)));
typedef uint uint4v __attribute__((ext_vector_type(4)));

#define SPH  32           // timesteps per phase
#define NIT  34           // 32 compute phases + 2 pipeline-drain iterations
#define XTW  36           // xsT row stride (floats): 144 B rows, 16B-aligned cols
#define BRW  12           // bits row stride (dwords): 48 B rows, 16B-aligned
#define C2W  48           // c2L row stride (floats)
#define TN   1000

// R21 = R20 (spikes as BITS) with compile fix: __builtin_amdgcn_writelane
// doesn't exist here -> predicated select (lane==s ? uniform : keep), which
// lowers to v_cmp + v_cndmask with SGPR src0. Design recap: conv waves
// ballot each step's spikes (2 ballots = 8p x 16c bits), lane s collects
// step s; ONE b64 LDS write per plane per wave per phase (6 writes total,
// was 96). GEMM reads 6 dwords/thread (b128+b64) and decodes bits->f16 0/1
// in-register (mul-spread). Channel map (c, c+8); K' = p*16+c unchanged ->
// BIT-IDENTICAL math (absmax must stay 0.015625).
//   waves 0-2 (192 thr): conv+LIF1(ph), channels (ct&7, +8), p=ct>>3
//   waves 3-8 (384 thr): FC GEMM(ph-1) + xsT staging (2-phase pipeline)
//   wave 3:              LIF2 scan(ph-2) after GEMM + final output.
// One barrier per iteration; producer->consumer 1 barrier apart.

#define LOADBLK(BUF, S)                                                 \
    _Pragma("unroll")                                                   \
    for (int k = 0; k < 7; ++k)                                         \
        BUF[k] = *(const f32x4*)(xcol + k * XTW + (S));

#define CONV4B(BUF, SB)                                                 \
    {                                                                   \
        float ca[4], cc[4];                                             \
        _Pragma("unroll")                                               \
        for (int dt = 0; dt < 4; ++dt) { ca[dt] = cb0; cc[dt] = cb1; }  \
        _Pragma("unroll")                                               \
        for (int k = 0; k < 7; ++k) {                                   \
            _Pragma("unroll")                                           \
            for (int dt = 0; dt < 4; ++dt) {                            \
                ca[dt] = fmaf(wk0[k], BUF[k][dt], ca[dt]);              \
                cc[dt] = fmaf(wk1[k], BUF[k][dt], cc[dt]);              \
            }                                                           \
        }                                                               \
        _Pragma("unroll")                                               \
        for (int dt = 0; dt < 4; ++dt) {                                \
            m1a = fmaf(0.9f, m1a, ca[dt] - spa);                        \
            spa = (m1a > 1.0f) ? 1.0f : 0.0f;                           \
            m1b = fmaf(0.9f, m1b, cc[dt] - spb);                        \
            spb = (m1b > 1.0f) ? 1.0f : 0.0f;                           \
            unsigned long long Ab = __ballot(m1a > 1.0f);               \
            unsigned long long Bb = __ballot(m1b > 1.0f);               \
            const int ssel = (SB) + dt;                                 \
            aLo = (lane == ssel) ? (uint)(Ab & 0xFFFFFFFFull) : aLo;    \
            aHi = (lane == ssel) ? (uint)(Ab >> 32)           : aHi;    \
            bLo = (lane == ssel) ? (uint)(Bb & 0xFFFFFFFFull) : bLo;    \
            bHi = (lane == ssel) ? (uint)(Bb >> 32)           : bHi;    \
        }                                                               \
    }

__global__ __launch_bounds__(576, 1) void snn_fwd(
    const float* __restrict__ x,      // (256,1000,30)
    const float* __restrict__ conv_w, // (16,1,7)
    const float* __restrict__ conv_b, // (16)
    const float* __restrict__ fc_w,   // (35,384)
    const float* __restrict__ fc_b,   // (35)
    float* __restrict__ out)          // (256,35)
{
    // bits[buf][plane][t][BRW dwords]: byte p of row = spike bits (8 ch) at (t,p)
    __shared__ __align__(16) uint  bits[2][2][SPH][BRW];   //  6144 B
    __shared__ __align__(16) float xsT[2][30][XTW];        //  8640 B
    __shared__ __align__(16) float c2L[2][SPH][C2W];       // 12288 B

    const int tid  = threadIdx.x;
    const int b    = blockIdx.x;
    const int wid  = tid >> 6;
    const int lane = tid & 63;

    // ---------- conv setup (wid<3): channels (cA=ct&7, cA+8), p = ct>>3 ----------
    const int ct = tid;              // 0..191 when wid<3
    const int cA = ct & 7;
    const int p  = ct >> 3;          // 0..23 (wave covers 8 consecutive p)
    float wk0[7], wk1[7];
    float cb0 = 0.f, cb1 = 0.f;
    if (wid < 3) {
#pragma unroll
        for (int k = 0; k < 7; ++k) {
            wk0[k] = conv_w[cA * 7 + k];
            wk1[k] = conv_w[(cA + 8) * 7 + k];
        }
        cb0 = conv_b[cA];
        cb1 = conv_b[cA + 8];
    }

    // ---------- FC setup (wid 3..8): g=(wid-3): m=g>>1 (M-tile), tb=g&1 ----------
    const int g  = wid - 3;
    const int m  = g >> 1;
    const int tb = g & 1;
    const int nL = lane & 15;        // B col (t_local); C col
    const int q  = lane >> 4;        // quad: k = q*8 + j
    half8 A[12];
    if (wid >= 3) {
        const int o = m * 16 + nL;
#pragma unroll
        for (int kt = 0; kt < 12; ++kt) {
            half8 a;
#pragma unroll
            for (int j = 0; j < 8; ++j) {
                int Kp = kt * 32 + q * 8 + j;    // K' = p*16 + c
                int Kc = Kp & 15;                 // channel
                int Kq = Kp >> 4;                 // position
                a[j] = (o < 35) ? (_Float16)fc_w[o * 384 + Kc * 24 + Kq]
                                : (_Float16)0.f;
            }
            A[kt] = a;
        }
    }
    const float fcb = (wid == 3 && lane < 35) ? fc_b[lane] : 0.f;

    // ---------- staging setup (wid>=3): st = tid-192 in 0..383, 3 floats each ----------
    const int st = tid - 192;
    int fs[3], fl[3];
    if (wid >= 3) {
#pragma unroll
        for (int r = 0; r < 3; ++r) {
            int f = st + 384 * r;    // 0..1151
            fs[r] = f / 30;
            fl[r] = f % 30;
        }
    }

    // ---------- state ----------
    float m1a = 0.f, spa = 0.f;      // LIF1 channel cA
    float m1b = 0.f, spb = 0.f;      // LIF1 channel cA+8
    float mem2 = 0.f, accO = 0.f;    // LIF2 (wave3 lanes<35)
    float xr[3];                     // staging regs, data phase ph+1

    const float* xb = x + (size_t)b * (TN * 30);

    // ---------- prologue (wid>=3): stage xsT[0]; issue loads for data phase 1 ----------
    if (wid >= 3) {
#pragma unroll
        for (int r = 0; r < 3; ++r) {
            int f = st + 384 * r;
            if (f < 960) xsT[0][fl[r]][fs[r]] = xb[f];     // t < 32 < TN
        }
#pragma unroll
        for (int r = 0; r < 3; ++r) {
            int f = st + 384 * r;
            xr[r] = (f < 960) ? xb[960 + f] : 0.f;         // t < 64 < TN
        }
    }
    __syncthreads();

#pragma unroll 1
    for (int ph = 0; ph < NIT; ++ph) {
        if (wid < 3) {
            // ===== conv+LIF1(ph): 8 blocks of 4 steps; bit-collect via cndmask =====
            if (ph < 32) {
                const float* xcol = &xsT[ph & 1][p][0];
                uint aLo = 0, aHi = 0, bLo = 0, bHi = 0;

                f32x4 bufA[7], bufB[7];
                LOADBLK(bufA, 0)
#pragma unroll
                for (int blk = 0; blk < 8; blk += 2) {
                    LOADBLK(bufB, (blk + 1) * 4)
                    CONV4B(bufA, blk * 4)
                    if (blk + 2 < 8) { LOADBLK(bufA, (blk + 2) * 4) }
                    CONV4B(bufB, (blk + 1) * 4)
                }
                // lane s (s<32) holds step s's 8 bytes per plane; one b64 each
                if (lane < 32) {
                    uint2v va; va.x = aLo; va.y = aHi;
                    uint2v vb; vb.x = bLo; vb.y = bHi;
                    *(uint2v*)&bits[ph & 1][0][lane][wid * 2] = va;
                    *(uint2v*)&bits[ph & 1][1][lane][wid * 2] = vb;
                }
            }
        } else {
            // ====== staging loads for data phase ph+2 issued first (latency) ======
            const bool ldg = (ph <= 29);
            float xn[3];
            if (ldg) {
                const float* src = xb + (size_t)(ph + 2) * (SPH * 30);
#pragma unroll
                for (int r = 0; r < 3; ++r) {
                    int f = st + 384 * r;
                    int t = (ph + 2) * SPH + fs[r];
                    xn[r] = (f < 960 && t < TN) ? src[f] : 0.f;
                }
            }
            // ============ GEMM(ph-1): bit-tile read + in-register decode ============
            if (ph >= 1 && ph <= 32) {
                const int t = tb * 16 + nL;
                const uint* bb = &bits[(ph - 1) & 1][q & 1][t][0];
                uint4v dA = *(const uint4v*)bb;          // dwords 0-3 (p 0..15)
                uint2v dB = *(const uint2v*)(bb + 4);    // dwords 4-5 (p 16..23)
                uint d[6] = {dA.x, dA.y, dA.z, dA.w, dB.x, dB.y};
                const uint qsh = (uint)((q >> 1) * 8);
                f32x4 acc = {0.f, 0.f, 0.f, 0.f};
#pragma unroll
                for (int kt = 0; kt < 12; ++kt) {
                    // byte = spikes for channels (q&1)*8.. at p = 2kt+(q>>1)
                    uint mm = (d[kt >> 1] >> (qsh + 16 * (kt & 1))) & 0xFFu;
                    // spread bits to 0/1 bytes, then bytes to f16 0/1.0
                    uint sl  = ((mm & 0xFu) * 0x00204081u) & 0x01010101u;        // bits 0-3
                    uint sh2 = (((mm >> 4) & 0xFu) * 0x00204081u) & 0x01010101u; // bits 4-7
                    uint slh = sl >> 16, shh = sh2 >> 16;
                    uint w0 = (sl  & 1u) * 0x3C00u | (sl  & 0x100u) * 0x3C0000u;
                    uint w1 = (slh & 1u) * 0x3C00u | (slh & 0x100u) * 0x3C0000u;
                    uint w2 = (sh2 & 1u) * 0x3C00u | (sh2 & 0x100u) * 0x3C0000u;
                    uint w3 = (shh & 1u) * 0x3C00u | (shh & 0x100u) * 0x3C0000u;
                    uint4v wv; wv.x = w0; wv.y = w1; wv.z = w2; wv.w = w3;
                    half8 Bf = __builtin_bit_cast(half8, wv);
                    acc = __builtin_amdgcn_mfma_f32_16x16x32_f16(A[kt], Bf, acc, 0, 0, 0);
                }
                // C/D: col = lane&15 (t_local), row = q*4+i (o_local)
                float* cd = &c2L[(ph - 1) & 1][0][0];
                *(f32x4*)(cd + (tb * 16 + nL) * C2W + m * 16 + q * 4) = acc;
            }
            // =================== LIF2 scan(ph-2) (wave 3 lanes<35) ===================
            if (wid == 3 && lane < 35 && ph >= 2) {
                const float* cs = &c2L[(ph - 2) & 1][0][0];
                float v[SPH];
#pragma unroll
                for (int j = 0; j < SPH; ++j) v[j] = cs[j * C2W + lane];
                const int tbase = (ph - 2) * SPH;
#pragma unroll
                for (int j = 0; j < SPH; ++j) {
                    float r2 = (mem2 > 1.0f) ? 1.0f : 0.0f;
                    mem2 = 0.9f * mem2 + (v[j] + fcb) - r2;
                    if (tbase + j < TN) accO += mem2;
                }
            }
            // ====== staging store (data ph+1, loaded last phase); then rotate ======
            if (ph <= 30) {
                float* dst = &xsT[(ph + 1) & 1][0][0];
#pragma unroll
                for (int r = 0; r < 3; ++r) {
                    int f = st + 384 * r;
                    if (f < 960) dst[fl[r] * XTW + fs[r]] = xr[r];
                }
            }
            if (ldg) {
#pragma unroll
                for (int r = 0; r < 3; ++r) xr[r] = xn[r];
            }
        }
        __syncthreads();
    }

    if (wid == 3 && lane < 35) out[b * 35 + lane] = accO * (1.0f / (float)TN);
}

extern "C" void kernel_launch(void* const* d_in, const int* in_sizes, int n_in,
                              void* d_out, int out_size, void* d_ws, size_t ws_size,
                              hipStream_t stream) {
    const float* x      = (const float*)d_in[0];
    const float* conv_w = (const float*)d_in[1];
    const float* conv_b = (const float*)d_in[2];
    const float* fc_w   = (const float*)d_in[3];
    const float* fc_b   = (const float*)d_in[4];
    float* out          = (float*)d_out;

    snn_fwd<<<256, 576, 0, stream>>>(x, conv_w, conv_b, fc_w, fc_b, out);
}

// Round 11
// 150.248 us; speedup vs baseline: 1.5053x; 1.5053x over previous
//
#include <hip/hip_runtime.h>

typedef _Float16 half8 __attribute__((ext_vector_type(8)));
typedef float f32x4 __attribute__((ext_vector_type(4)));

#define SPH  32           // timesteps per phase
#define NIT  34           // 32 compute phases + 2 pipeline-drain iterations
#define SPKW 392          // spk row stride f16: 384 + 8 pad (784 B rows, 16B-aligned)
#define XTW  36           // xsT row stride (floats): 144 B rows, 16B-aligned cols
#define C2W  48           // c2L row stride (floats)
#define TN   1000

// R22 = R19 + cross-barrier conv read pipeline + setprio(1) on conv waves.
// R21 (bit spikes) reverted: VGPR spill cliff (28MB scratch). Theory: conv
// wave = critical path; its post-barrier reads queue behind the CU-wide
// LDS burst (~1-2k cyc start delay). Fix: xsT TRIPLE-buffered, staged TWO
// phases ahead (store d=ph+2 during ph), so conv can issue blocks 0-1 of
// phase ph+1 BEFORE the barrier (buffer complete since end of ph-1) and
// compute immediately after it. Conv reads stay 2 blocks ahead across the
// barrier. GEMM/spk/scan bit-identical to R19 (absmax must be 0.015625).
//   waves 0-2 (192 thr): conv+LIF1(ph), 2 ch/thread (cpair=ct&7, p=ct>>3)
//   waves 3-8 (384 thr): FC GEMM(ph-1) + xsT staging (3-phase pipeline:
//                        load d=ph+3 -> regs; store d=ph+2 -> xsT[(ph+2)%3])
//   wave 3:              LIF2 scan(ph-2) after GEMM + final output.
// One barrier per iteration.

#define LOADBLK(BUF, S)                                                 \
    _Pragma("unroll")                                                   \
    for (int k = 0; k < 7; ++k)                                         \
        BUF[k] = *(const f32x4*)(xcol + k * XTW + (S));

#define LOADBLKN(BUF, S)                                                \
    _Pragma("unroll")                                                   \
    for (int k = 0; k < 7; ++k)                                         \
        BUF[k] = *(const f32x4*)(xcolN + k * XTW + (S));

#define CONV4(BUF, SB)                                                  \
    {                                                                   \
        float ca[4], cc[4];                                             \
        _Pragma("unroll")                                               \
        for (int dt = 0; dt < 4; ++dt) { ca[dt] = cb0; cc[dt] = cb1; }  \
        _Pragma("unroll")                                               \
        for (int k = 0; k < 7; ++k) {                                   \
            _Pragma("unroll")                                           \
            for (int dt = 0; dt < 4; ++dt) {                            \
                ca[dt] = fmaf(wk0[k], BUF[k][dt], ca[dt]);              \
                cc[dt] = fmaf(wk1[k], BUF[k][dt], cc[dt]);              \
            }                                                           \
        }                                                               \
        _Pragma("unroll")                                               \
        for (int dt = 0; dt < 4; ++dt) {                                \
            m1a = fmaf(0.9f, m1a, ca[dt] - spa);                        \
            spa = (m1a > 1.0f) ? 1.0f : 0.0f;                           \
            m1b = fmaf(0.9f, m1b, cc[dt] - spb);                        \
            spb = (m1b > 1.0f) ? 1.0f : 0.0f;                           \
            unsigned int pk = (m1a > 1.0f ? 0x00003C00u : 0u) |         \
                              (m1b > 1.0f ? 0x3C000000u : 0u);          \
            sdst[((SB) + dt) * (SPKW / 2)] = pk;                        \
        }                                                               \
    }

__global__ __launch_bounds__(576, 1) void snn_fwd(
    const float* __restrict__ x,      // (256,1000,30)
    const float* __restrict__ conv_w, // (16,1,7)
    const float* __restrict__ conv_b, // (16)
    const float* __restrict__ fc_w,   // (35,384)
    const float* __restrict__ fc_b,   // (35)
    float* __restrict__ out)          // (256,35)
{
    __shared__ __align__(16) _Float16 spk[2][SPH][SPKW];   // 50176 B
    __shared__ __align__(16) float    xsT[3][30][XTW];     // 12960 B
    __shared__ __align__(16) float    c2L[2][SPH][C2W];    // 12288 B

    const int tid  = threadIdx.x;
    const int b    = blockIdx.x;
    const int wid  = tid >> 6;
    const int lane = tid & 63;

    // ---------- conv setup (wid<3): thread = (cpair=ct&7, p=ct>>3), 2 channels ----------
    const int ct    = tid;           // 0..191 when wid<3
    const int cpair = ct & 7;
    const int p     = ct >> 3;       // 0..23
    const int c0    = cpair * 2;
    float wk0[7], wk1[7];
    float cb0 = 0.f, cb1 = 0.f;
    if (wid < 3) {
        __builtin_amdgcn_s_setprio(1);       // bias scheduler toward critical conv waves
#pragma unroll
        for (int k = 0; k < 7; ++k) {
            wk0[k] = conv_w[c0 * 7 + k];
            wk1[k] = conv_w[(c0 + 1) * 7 + k];
        }
        cb0 = conv_b[c0];
        cb1 = conv_b[c0 + 1];
    }

    // ---------- FC setup (wid 3..8): g=(wid-3): m=g>>1 (M-tile), tb=g&1 ----------
    const int g  = wid - 3;
    const int m  = g >> 1;
    const int tb = g & 1;
    const int nL = lane & 15;        // B col (t_local); C col
    const int q  = lane >> 4;        // quad: k = q*8 + j
    half8 A[12];
    if (wid >= 3) {
        const int o = m * 16 + nL;
#pragma unroll
        for (int kt = 0; kt < 12; ++kt) {
            half8 a;
#pragma unroll
            for (int j = 0; j < 8; ++j) {
                int Kp = kt * 32 + q * 8 + j;    // permuted K index (p*16+c)
                int Kc = Kp & 15;                 // channel
                int Kq = Kp >> 4;                 // position
                a[j] = (o < 35) ? (_Float16)fc_w[o * 384 + Kc * 24 + Kq]
                                : (_Float16)0.f;
            }
            A[kt] = a;
        }
    }
    const float fcb = (wid == 3 && lane < 35) ? fc_b[lane] : 0.f;

    // ---------- staging setup (wid>=3): st = tid-192 in 0..383, 3 floats each ----------
    const int st = tid - 192;
    int fs[3], fl[3];
    if (wid >= 3) {
#pragma unroll
        for (int r = 0; r < 3; ++r) {
            int f = st + 384 * r;    // 0..1151
            fs[r] = f / 30;
            fl[r] = f % 30;
        }
    }

    // ---------- state ----------
    float m1a = 0.f, spa = 0.f;      // LIF1 channel c0
    float m1b = 0.f, spb = 0.f;      // LIF1 channel c0+1
    float mem2 = 0.f, accO = 0.f;    // LIF2 (wave3 lanes<35)
    float xr[3];                     // staging regs, data phase ph+2
    f32x4 bufA[7], bufB[7];          // conv read pipeline (persistent across phases)

    const float* xb = x + (size_t)b * (TN * 30);

    // ---------- prologue ----------
    if (wid >= 3) {
        // stage xsT[0] (data phase 0) and xsT[1] (data phase 1)
#pragma unroll
        for (int d = 0; d < 2; ++d) {
#pragma unroll
            for (int r = 0; r < 3; ++r) {
                int f = st + 384 * r;
                if (f < 960) xsT[d][fl[r]][fs[r]] = xb[d * 960 + f];   // t < 64 < TN
            }
        }
        // regs carry data phase 2
#pragma unroll
        for (int r = 0; r < 3; ++r) {
            int f = st + 384 * r;
            xr[r] = (f < 960) ? xb[2 * 960 + f] : 0.f;                 // t < 96 < TN
        }
    }
    __syncthreads();

    // conv: prime the 2-deep pipeline for phase 0 (blocks 0 and 1)
    if (wid < 3) {
        const float* xcol = &xsT[0][p][0];
        LOADBLK(bufA, 0)
        LOADBLK(bufB, 4)
    }

#pragma unroll 1
    for (int ph = 0; ph < NIT; ++ph) {
        if (wid < 3) {
            // ===== conv+LIF1(ph): 8 blocks; reads stay 2 blocks ahead, crossing =====
            // ===== into xsT[(ph+1)%3] (complete since end of ph-1) pre-barrier =====
            if (ph < 32) {
                const float* xcol  = &xsT[ph % 3][p][0];
                const float* xcolN = &xsT[(ph + 1) % 3][p][0];
                unsigned int* sdst =
                    (unsigned int*)&spk[ph & 1][0][p * 16 + c0];
#pragma unroll
                for (int h = 0; h < 4; ++h) {
                    const int blkA = 2 * h, blkB = 2 * h + 1;
                    CONV4(bufA, blkA * 4)
                    if (blkA + 2 < 8) { LOADBLK(bufA, (blkA + 2) * 4) }
                    else              { LOADBLKN(bufA, (blkA - 6) * 4) }
                    CONV4(bufB, blkB * 4)
                    if (blkB + 2 < 8) { LOADBLK(bufB, (blkB + 2) * 4) }
                    else              { LOADBLKN(bufB, (blkB - 6) * 4) }
                }
            }
        } else {
            // ====== staging loads for data phase ph+3 issued first (latency) ======
            const bool ldg = (ph <= 28);
            float xn[3];
            if (ldg) {
                const float* src = xb + (size_t)(ph + 3) * (SPH * 30);
#pragma unroll
                for (int r = 0; r < 3; ++r) {
                    int f = st + 384 * r;
                    int t = (ph + 3) * SPH + fs[r];
                    xn[r] = (f < 960 && t < TN) ? src[f] : 0.f;
                }
            }
            // =================== GEMM(ph-1): this wave's (m, tb) ===================
            if (ph >= 1 && ph <= 32) {
                const _Float16* sb = &spk[(ph - 1) & 1][0][0];
                half8 B[12];
#pragma unroll
                for (int kt = 0; kt < 12; ++kt)
                    B[kt] = *(const half8*)(sb + (tb * 16 + nL) * SPKW + kt * 32 + q * 8);
                f32x4 acc = {0.f, 0.f, 0.f, 0.f};
#pragma unroll
                for (int kt = 0; kt < 12; ++kt)
                    acc = __builtin_amdgcn_mfma_f32_16x16x32_f16(A[kt], B[kt], acc, 0, 0, 0);
                // C/D: col = lane&15 (t_local), row = q*4+i (o_local)
                float* cd = &c2L[(ph - 1) & 1][0][0];
                *(f32x4*)(cd + (tb * 16 + nL) * C2W + m * 16 + q * 4) = acc;
            }
            // =================== LIF2 scan(ph-2) (wave 3 lanes<35) ===================
            if (wid == 3 && lane < 35 && ph >= 2) {
                const float* cs = &c2L[(ph - 2) & 1][0][0];
                float v[SPH];
#pragma unroll
                for (int j = 0; j < SPH; ++j) v[j] = cs[j * C2W + lane];
                const int tbase = (ph - 2) * SPH;
#pragma unroll
                for (int j = 0; j < SPH; ++j) {
                    float r2 = (mem2 > 1.0f) ? 1.0f : 0.0f;
                    mem2 = 0.9f * mem2 + (v[j] + fcb) - r2;
                    if (tbase + j < TN) accO += mem2;
                }
            }
            // ====== staging store (data phase ph+2, loaded a phase ago) ======
            if (ph <= 29) {
                float* dst = &xsT[(ph + 2) % 3][0][0];
#pragma unroll
                for (int r = 0; r < 3; ++r) {
                    int f = st + 384 * r;
                    if (f < 960) dst[fl[r] * XTW + fs[r]] = xr[r];
                }
            }
            if (ldg) {
#pragma unroll
                for (int r = 0; r < 3; ++r) xr[r] = xn[r];
            }
        }
        __syncthreads();
    }

    if (wid == 3 && lane < 35) out[b * 35 + lane] = accO * (1.0f / (float)TN);
}

extern "C" void kernel_launch(void* const* d_in, const int* in_sizes, int n_in,
                              void* d_out, int out_size, void* d_ws, size_t ws_size,
                              hipStream_t stream) {
    const float* x      = (const float*)d_in[0];
    const float* conv_w = (const float*)d_in[1];
    const float* conv_b = (const float*)d_in[2];
    const float* fc_w   = (const float*)d_in[3];
    const float* fc_b   = (const float*)d_in[4];
    float* out          = (float*)d_out;

    snn_fwd<<<256, 576, 0, stream>>>(x, conv_w, conv_b, fc_w, fc_b, out);
}

// Round 12
// 146.794 us; speedup vs baseline: 1.5407x; 1.0235x over previous
//
#include <hip/hip_runtime.h>

typedef _Float16 half8 __attribute__((ext_vector_type(8)));
typedef float f32x4 __attribute__((ext_vector_type(4)));

#define SPH  48           // timesteps per phase (R23: 34->23 iterations)
#define NIT  23           // 21 compute phases + 2 pipeline-drain iterations
#define SPKW 392          // spk row stride f16: 384 + 8 pad (784 B rows, 16B-aligned)
#define XTW  52           // xsT row stride (floats): 208 B rows, 16B-aligned cols
#define C2W  48           // c2L row stride (floats)
#define TN   1000

// R23: amortize per-phase gap (~1.4k cyc x 34) with SPH=48, using a
// SPILL-SAFE layout (lesson of R17/R18/R22: any persistent/looped register
// state -> scratch cliff). 768 thr = 12 waves; every wave's per-phase
// register profile <= R19's:
//   waves 0-2  (192 thr): conv+LIF1(ph), 2 ch/thread (cpair=ct&7, p=ct>>3),
//                         12 blocks of 4 steps, per-phase 2-deep read pipe.
//   waves 3-11 (576 thr): FC GEMM(ph-1), ONE 16x16 tile/wave (m=g/3, tb=g%3,
//                         single A[12]); + xsT staging (3 floats/thread,
//                         2-phase pipeline, guard f<1440).
//   wave 3:              LIF2 scan(ph-2) after GEMM + final output.
// One barrier per iteration; producer->consumer 1 barrier apart.
// Tripwire: WRITE_SIZE must stay ~42KB; >1MB = spill -> revert to R19.

#define LOADBLK(BUF, S)                                                 \
    _Pragma("unroll")                                                   \
    for (int k = 0; k < 7; ++k)                                         \
        BUF[k] = *(const f32x4*)(xcol + k * XTW + (S));

#define CONV4(BUF, SB)                                                  \
    {                                                                   \
        float ca[4], cc[4];                                             \
        _Pragma("unroll")                                               \
        for (int dt = 0; dt < 4; ++dt) { ca[dt] = cb0; cc[dt] = cb1; }  \
        _Pragma("unroll")                                               \
        for (int k = 0; k < 7; ++k) {                                   \
            _Pragma("unroll")                                           \
            for (int dt = 0; dt < 4; ++dt) {                            \
                ca[dt] = fmaf(wk0[k], BUF[k][dt], ca[dt]);              \
                cc[dt] = fmaf(wk1[k], BUF[k][dt], cc[dt]);              \
            }                                                           \
        }                                                               \
        _Pragma("unroll")                                               \
        for (int dt = 0; dt < 4; ++dt) {                                \
            m1a = fmaf(0.9f, m1a, ca[dt] - spa);                        \
            spa = (m1a > 1.0f) ? 1.0f : 0.0f;                           \
            m1b = fmaf(0.9f, m1b, cc[dt] - spb);                        \
            spb = (m1b > 1.0f) ? 1.0f : 0.0f;                           \
            unsigned int pk = (m1a > 1.0f ? 0x00003C00u : 0u) |         \
                              (m1b > 1.0f ? 0x3C000000u : 0u);          \
            sdst[((SB) + dt) * (SPKW / 2)] = pk;                        \
        }                                                               \
    }

__global__ __launch_bounds__(768, 1) void snn_fwd(
    const float* __restrict__ x,      // (256,1000,30)
    const float* __restrict__ conv_w, // (16,1,7)
    const float* __restrict__ conv_b, // (16)
    const float* __restrict__ fc_w,   // (35,384)
    const float* __restrict__ fc_b,   // (35)
    float* __restrict__ out)          // (256,35)
{
    __shared__ __align__(16) _Float16 spk[2][SPH][SPKW];   // 75264 B
    __shared__ __align__(16) float    xsT[2][30][XTW];     // 12480 B
    __shared__ __align__(16) float    c2L[2][SPH][C2W];    // 18432 B

    const int tid  = threadIdx.x;
    const int b    = blockIdx.x;
    const int wid  = tid >> 6;
    const int lane = tid & 63;

    // ---------- conv setup (wid<3): thread = (cpair=ct&7, p=ct>>3), 2 channels ----------
    const int ct    = tid;           // 0..191 when wid<3
    const int cpair = ct & 7;
    const int p     = ct >> 3;       // 0..23
    const int c0    = cpair * 2;
    float wk0[7], wk1[7];
    float cb0 = 0.f, cb1 = 0.f;
    if (wid < 3) {
#pragma unroll
        for (int k = 0; k < 7; ++k) {
            wk0[k] = conv_w[c0 * 7 + k];
            wk1[k] = conv_w[(c0 + 1) * 7 + k];
        }
        cb0 = conv_b[c0];
        cb1 = conv_b[c0 + 1];
    }

    // ---------- FC setup (wid 3..11): g=(wid-3): m=g/3, tb=g%3, ONE tile ----------
    const int g  = wid - 3;
    const int m  = g / 3;            // 0..2
    const int tb = g % 3;            // 0..2
    const int nL = lane & 15;        // B col (t_local); C col
    const int q  = lane >> 4;        // quad: k = q*8 + j
    half8 A[12];
    if (wid >= 3) {
        const int o = m * 16 + nL;
#pragma unroll
        for (int kt = 0; kt < 12; ++kt) {
            half8 a;
#pragma unroll
            for (int j = 0; j < 8; ++j) {
                int Kp = kt * 32 + q * 8 + j;    // permuted K index (p*16+c)
                int Kc = Kp & 15;                 // channel
                int Kq = Kp >> 4;                 // position
                a[j] = (o < 35) ? (_Float16)fc_w[o * 384 + Kc * 24 + Kq]
                                : (_Float16)0.f;
            }
            A[kt] = a;
        }
    }
    const float fcb = (wid == 3 && lane < 35) ? fc_b[lane] : 0.f;

    // ---------- staging setup (wid>=3): st = tid-192 in 0..575, 3 floats each ----------
    const int st = tid - 192;
    int fs[3], fl[3];
    if (wid >= 3) {
#pragma unroll
        for (int r = 0; r < 3; ++r) {
            int f = st + 576 * r;    // 0..1727 (1440 used)
            fs[r] = f / 30;          // t_local 0..47 (for f<1440)
            fl[r] = f % 30;
        }
    }

    // ---------- state ----------
    float m1a = 0.f, spa = 0.f;      // LIF1 channel c0
    float m1b = 0.f, spb = 0.f;      // LIF1 channel c0+1
    float mem2 = 0.f, accO = 0.f;    // LIF2 (wave3 lanes<35)
    float xr[3];                     // staging regs, data phase ph+1

    const float* xb = x + (size_t)b * (TN * 30);

    // ---------- prologue (wid>=3): stage xsT[0]; issue loads for data phase 1 ----------
    if (wid >= 3) {
#pragma unroll
        for (int r = 0; r < 3; ++r) {
            int f = st + 576 * r;
            if (f < 1440) xsT[0][fl[r]][fs[r]] = xb[f];    // t < 48 < TN
        }
#pragma unroll
        for (int r = 0; r < 3; ++r) {
            int f = st + 576 * r;
            xr[r] = (f < 1440) ? xb[1440 + f] : 0.f;       // t < 96 < TN
        }
    }
    __syncthreads();

#pragma unroll 1
    for (int ph = 0; ph < NIT; ++ph) {
        if (wid < 3) {
            // ===== conv+LIF1(ph): 12 blocks of 4 steps, 2-deep read pipeline =====
            if (ph < 21) {
                const float* xcol = &xsT[ph & 1][p][0];
                unsigned int* sdst =
                    (unsigned int*)&spk[ph & 1][0][p * 16 + c0];

                f32x4 bufA[7], bufB[7];
                LOADBLK(bufA, 0)
#pragma unroll
                for (int blk = 0; blk < 12; blk += 2) {
                    LOADBLK(bufB, (blk + 1) * 4)
                    CONV4(bufA, blk * 4)
                    if (blk + 2 < 12) { LOADBLK(bufA, (blk + 2) * 4) }
                    CONV4(bufB, (blk + 1) * 4)
                }
            }
        } else {
            // ====== staging loads for data phase ph+2 issued first (latency) ======
            const bool ldg = (ph <= 18);
            float xn[3];
            if (ldg) {
                const float* src = xb + (size_t)(ph + 2) * (SPH * 30);
#pragma unroll
                for (int r = 0; r < 3; ++r) {
                    int f = st + 576 * r;
                    int t = (ph + 2) * SPH + fs[r];
                    xn[r] = (f < 1440 && t < TN) ? src[f] : 0.f;
                }
            }
            // =================== GEMM(ph-1): this wave's (m, tb) ===================
            if (ph >= 1 && ph <= 21) {
                const _Float16* sb = &spk[(ph - 1) & 1][0][0];
                half8 B[12];
#pragma unroll
                for (int kt = 0; kt < 12; ++kt)
                    B[kt] = *(const half8*)(sb + (tb * 16 + nL) * SPKW + kt * 32 + q * 8);
                f32x4 acc = {0.f, 0.f, 0.f, 0.f};
#pragma unroll
                for (int kt = 0; kt < 12; ++kt)
                    acc = __builtin_amdgcn_mfma_f32_16x16x32_f16(A[kt], B[kt], acc, 0, 0, 0);
                // C/D: col = lane&15 (t_local), row = q*4+i (o_local)
                float* cd = &c2L[(ph - 1) & 1][0][0];
                *(f32x4*)(cd + (tb * 16 + nL) * C2W + m * 16 + q * 4) = acc;
            }
            // =================== LIF2 scan(ph-2) (wave 3 lanes<35) ===================
            if (wid == 3 && lane < 35 && ph >= 2) {
                const float* cs = &c2L[(ph - 2) & 1][0][0];
                float v[SPH];
#pragma unroll
                for (int j = 0; j < SPH; ++j) v[j] = cs[j * C2W + lane];
                const int tbase = (ph - 2) * SPH;
#pragma unroll
                for (int j = 0; j < SPH; ++j) {
                    float r2 = (mem2 > 1.0f) ? 1.0f : 0.0f;
                    mem2 = 0.9f * mem2 + (v[j] + fcb) - r2;
                    if (tbase + j < TN) accO += mem2;
                }
            }
            // ====== staging store (data ph+1, loaded last phase); then rotate ======
            if (ph <= 19) {
                float* dst = &xsT[(ph + 1) & 1][0][0];
#pragma unroll
                for (int r = 0; r < 3; ++r) {
                    int f = st + 576 * r;
                    if (f < 1440) dst[fl[r] * XTW + fs[r]] = xr[r];
                }
            }
            if (ldg) {
#pragma unroll
                for (int r = 0; r < 3; ++r) xr[r] = xn[r];
            }
        }
        __syncthreads();
    }

    if (wid == 3 && lane < 35) out[b * 35 + lane] = accO * (1.0f / (float)TN);
}

extern "C" void kernel_launch(void* const* d_in, const int* in_sizes, int n_in,
                              void* d_out, int out_size, void* d_ws, size_t ws_size,
                              hipStream_t stream) {
    const float* x      = (const float*)d_in[0];
    const float* conv_w = (const float*)d_in[1];
    const float* conv_b = (const float*)d_in[2];
    const float* fc_w   = (const float*)d_in[3];
    const float* fc_b   = (const float*)d_in[4];
    float* out          = (float*)d_out;

    snn_fwd<<<256, 768, 0, stream>>>(x, conv_w, conv_b, fc_w, fc_b, out);
}